// Round 1
// baseline (97.304 us; speedup 1.0000x reference)
//
#include <hip/hip_runtime.h>

// BinNormTrain: per-row solve sum_d sigmoid(x[d] + nu) == K (K=64) over rows of
// x:[16384,256] f32, then output sigmoid(x + nu). Reference does branch-bisection
// to bracket width <= 1e-4; test threshold on outputs is ~1.96e-2, and
// |d sigmoid/d nu| <= 0.25, so any root solve accurate to ~1e-5 matches.
// Guaranteed bracket (this is why DELTA=7): f(-max-7) < 0 < f(-min+7).

#define B_ROWS 16384
#define D_COLS 256
#define KF 64.0f
#define DELTA_F 7.0f
#define N_BISECT 30

__device__ __forceinline__ float fast_sigmoid(float t) {
    // sigmoid(t) = 1 / (1 + exp(-t)); native exp + hw rcp (~1 ulp each).
    return __builtin_amdgcn_rcpf(1.0f + __expf(-t));
}

__global__ __launch_bounds__(256) void binnorm_kernel(const float* __restrict__ x,
                                                      float* __restrict__ out) {
    const int tid = threadIdx.x;
    const int lane = tid & 15;        // lane within 16-lane row group
    const int rowLocal = tid >> 4;    // 16 rows per 256-thread block
    const int row = (blockIdx.x << 4) + rowLocal;

    const float4* xr = reinterpret_cast<const float4*>(x + (size_t)row * D_COLS);
    float4* orow = reinterpret_cast<float4*>(out + (size_t)row * D_COLS);

    // Load 16 elements per lane (4 x float4, coalesced: 16 lanes cover 16
    // consecutive float4s per j). Row stays in registers for the whole solve.
    float xv[16];
#pragma unroll
    for (int j = 0; j < 4; ++j) {
        float4 v = xr[lane + (j << 4)];
        xv[4 * j + 0] = v.x;
        xv[4 * j + 1] = v.y;
        xv[4 * j + 2] = v.z;
        xv[4 * j + 3] = v.w;
    }

    // Row max/min -> guaranteed bracket [-max-7, -min+7].
    float mx = xv[0], mn = xv[0];
#pragma unroll
    for (int e = 1; e < 16; ++e) {
        mx = fmaxf(mx, xv[e]);
        mn = fminf(mn, xv[e]);
    }
#pragma unroll
    for (int m = 1; m <= 8; m <<= 1) {
        mx = fmaxf(mx, __shfl_xor(mx, m));
        mn = fminf(mn, __shfl_xor(mn, m));
    }

    float lo = -mx - DELTA_F;
    float hi = -mn + DELTA_F;

    for (int it = 0; it < N_BISECT; ++it) {
        const float nu = 0.5f * (lo + hi);
        float s = 0.0f;
#pragma unroll
        for (int e = 0; e < 16; ++e) s += fast_sigmoid(xv[e] + nu);
        // Reduce across the 16-lane group (xor masks stay within the group).
        s += __shfl_xor(s, 1);
        s += __shfl_xor(s, 2);
        s += __shfl_xor(s, 4);
        s += __shfl_xor(s, 8);
        if (s < KF) lo = nu; else hi = nu;  // uniform across group -> cndmask
    }
    const float nu = 0.5f * (lo + hi);

#pragma unroll
    for (int j = 0; j < 4; ++j) {
        float4 o;
        o.x = fast_sigmoid(xv[4 * j + 0] + nu);
        o.y = fast_sigmoid(xv[4 * j + 1] + nu);
        o.z = fast_sigmoid(xv[4 * j + 2] + nu);
        o.w = fast_sigmoid(xv[4 * j + 3] + nu);
        orow[lane + (j << 4)] = o;
    }
}

extern "C" void kernel_launch(void* const* d_in, const int* in_sizes, int n_in,
                              void* d_out, int out_size, void* d_ws, size_t ws_size,
                              hipStream_t stream) {
    const float* x = (const float*)d_in[0];
    float* out = (float*)d_out;
    binnorm_kernel<<<dim3(B_ROWS / 16), dim3(256), 0, stream>>>(x, out);
}

// Round 3
// 92.788 us; speedup vs baseline: 1.0487x; 1.0487x over previous
//
#include <hip/hip_runtime.h>

// BinNormTrain: per-row solve sum_d sigmoid(x[d] + nu) == K (K=64) over rows of
// x:[16384,256] f32, then output sigmoid(x + nu).
// R1: 16 lanes/row, 30 bisections -> 97 us PASS (latency-bound, 4 waves/SIMD).
// R2: 64 lanes/row + bracketed Newton FAIL: strict bounds test + `lo = nu`
//     before the test meant a converged step (cand == nu == lo) was treated
//     as out-of-bracket -> nu catapulted to midpoint of a one-sided bracket.
// R3: inclusive bounds test (converged point stays; NaN/inf still fall through
//     to midpoint), 12 iters. Bracket [-max-7, -min+7] guaranteed: f(lo)<0<f(hi).

#define D_COLS 256
#define KF 64.0f
#define DELTA_F 7.0f
#define N_ITERS_NEWTON 12

__device__ __forceinline__ float fast_sigmoid(float t) {
    return __builtin_amdgcn_rcpf(1.0f + __expf(-t));
}

__global__ __launch_bounds__(256) void binnorm_kernel(const float* __restrict__ x,
                                                      float* __restrict__ out) {
    const int lane = threadIdx.x & 63;         // 64 lanes per row
    const int waveInBlock = threadIdx.x >> 6;  // 4 rows per block
    const int row = (blockIdx.x << 2) + waveInBlock;

    const float4* xr = reinterpret_cast<const float4*>(x + (size_t)row * D_COLS);
    float4 v = xr[lane];                       // 64 lanes x 16B = whole row, coalesced
    float xv[4] = {v.x, v.y, v.z, v.w};

    // One-time reductions: sum (initial guess), max/min (bracket).
    float sum = (xv[0] + xv[1]) + (xv[2] + xv[3]);
    float mx = fmaxf(fmaxf(xv[0], xv[1]), fmaxf(xv[2], xv[3]));
    float mn = fminf(fminf(xv[0], xv[1]), fminf(xv[2], xv[3]));
#pragma unroll
    for (int m = 1; m <= 32; m <<= 1) {
        sum += __shfl_xor(sum, m);
        mx = fmaxf(mx, __shfl_xor(mx, m));
        mn = fminf(mn, __shfl_xor(mn, m));
    }

    float lo = -mx - DELTA_F;                  // f(lo) <= 256*sigmoid(-7) - 64 < 0
    float hi = -mn + DELTA_F;                  // f(hi) >= 256*sigmoid(+7) - 64 > 0

    // Mean-field initial guess: sigmoid(mean + nu)*256 = 64 -> nu = ln(1/3) - mean.
    float nu = -1.09861229f - sum * (1.0f / 256.0f);
    nu = fminf(fmaxf(nu, lo + 1e-3f), hi - 1e-3f);

    for (int it = 0; it < N_ITERS_NEWTON; ++it) {
        float f = 0.0f, fp = 0.0f;
#pragma unroll
        for (int e = 0; e < 4; ++e) {
            float s = fast_sigmoid(xv[e] + nu);
            f += s;
            fp += fmaf(-s, s, s);              // sigma*(1-sigma)
        }
#pragma unroll
        for (int m = 1; m <= 32; m <<= 1) {
            f += __shfl_xor(f, m);
            fp += __shfl_xor(fp, m);
        }
        f -= KF;
        // Bracket update by sign (wave-uniform -> cndmask).
        if (f < 0.0f) lo = nu; else hi = nu;
        // Newton step; INCLUSIVE bounds so a converged (zero-length) step
        // stays put instead of being kicked to the midpoint. NaN/inf from
        // degenerate fp fail the test and fall back to bisection.
        float cand = nu - f * __builtin_amdgcn_rcpf(fp);
        if (!(cand >= lo && cand <= hi)) cand = 0.5f * (lo + hi);
        nu = cand;
    }

    float4 o;
    o.x = fast_sigmoid(xv[0] + nu);
    o.y = fast_sigmoid(xv[1] + nu);
    o.z = fast_sigmoid(xv[2] + nu);
    o.w = fast_sigmoid(xv[3] + nu);
    reinterpret_cast<float4*>(out + (size_t)row * D_COLS)[lane] = o;
}

extern "C" void kernel_launch(void* const* d_in, const int* in_sizes, int n_in,
                              void* d_out, int out_size, void* d_ws, size_t ws_size,
                              hipStream_t stream) {
    const float* x = (const float*)d_in[0];
    float* out = (float*)d_out;
    const int rows = 16384;
    binnorm_kernel<<<dim3(rows / 4), dim3(256), 0, stream>>>(x, out);
}